// Round 3
// baseline (250.237 us; speedup 1.0000x reference)
//
#include <hip/hip_runtime.h>
#include <hip/hip_bf16.h>

typedef __bf16 bf16x8 __attribute__((ext_vector_type(8)));
typedef __bf16 bf16x4 __attribute__((ext_vector_type(4)));
typedef float floatx4 __attribute__((ext_vector_type(4)));

#define AS1 __attribute__((address_space(1)))
#define AS3 __attribute__((address_space(3)))

#define CHUNK_B 16384   // 32 GEMM rows x 512 B (fp32)

// Problem: y[b,i] (256x128) = x[b,i] (256x128) @ W_i^T (128x128) + bias_i
// per (b,i) "region" = 256 GEMM rows x 512 B, contiguous 128 KB.
//
// Grid 512 = 8 channels (blockIdx&7 -> XCD-pinned W_i) x 64; block = 2 regions
// (b = 2j, 2j+1) = 512 rows = 16 chunks of 32 rows. 256 threads / 4 waves.
// LDS: W bf16 swizzled 32 KB + X fp32 ring 2x16 KB + bias = 66 KB -> 2 blocks/CU.
//
// X staged with global_load_lds width16: every instruction = 1 KB contiguous
// global footprint (lane-permuted by the XOR swizzle baked into the SOURCE
// address; LDS dest linear). Counted vmcnt (never 0) + raw s_barrier ring.
__global__ __launch_bounds__(256, 2)
void mcsl_kernel(const float* __restrict__ x,
                 const float* __restrict__ W,
                 const float* __restrict__ bias,
                 float* __restrict__ y)
{
    __shared__ __align__(16) unsigned char Wl[32768];        // bf16, 256 B/row, XOR-swizzled
    __shared__ __align__(16) unsigned char Xl[2 * CHUNK_B];  // fp32 ring, XOR-swizzled rows
    __shared__ __align__(16) float blds[128];

    const int tid  = threadIdx.x;
    const int i    = blockIdx.x & 7;
    const int j    = blockIdx.x >> 3;
    const int lane = tid & 63;
    const int wv   = tid >> 6;       // wave 0..3
    const int nrow = lane & 15;
    const int quad = lane >> 4;

    // ---- stage W_i: fp32 -> bf16, byte ^= (o&7)<<4 within each 256 B row ----
    // (reads are instruction-contiguous: consecutive lanes -> consecutive float4)
    {
        const float4* Wsrc = (const float4*)(W + (size_t)i * (128 * 128));
        #pragma unroll
        for (int it = 0; it < 16; ++it) {
            int idx = tid + it * 256;          // 4096 float4 total
            float4 w4 = Wsrc[idx];
            int o  = idx >> 5;                 // output feature row
            int b8 = (idx & 31) << 3;          // byte offset of 8 B granule
            int sw = b8 ^ ((o & 7) << 4);
            bf16x4 wq;
            wq[0] = (__bf16)w4.x; wq[1] = (__bf16)w4.y;
            wq[2] = (__bf16)w4.z; wq[3] = (__bf16)w4.w;
            *(bf16x4*)&Wl[o * 256 + sw] = wq;
        }
        if (tid < 128) blds[tid] = bias[i * 128 + tid];
    }

    const size_t xoff0 = ((size_t)(2 * j)     * 64 + i * 8) * 4096;  // floats
    const size_t xoff1 = ((size_t)(2 * j + 1) * 64 + i * 8) * 4096;

    // ---- STAGE(c): 4 global_load_lds(16B) per thread; 1 KB contiguous per
    // wave-instruction. Source address carries the inverse row-XOR swizzle so
    // LDS slot (row, b) holds global (row, b ^ ((row&7)<<4)).
#define STAGE(c) do {                                                            \
        const unsigned char* gb =                                               \
            (const unsigned char*)(x + (((c) & 8) ? xoff1 : xoff0))             \
            + (size_t)((c) & 7) * CHUNK_B;                                      \
        unsigned char* db = Xl + ((c) & 1) * CHUNK_B;                           \
        _Pragma("unroll")                                                       \
        for (int jj = 0; jj < 4; ++jj) {                                        \
            const int Lu = (jj * 256 + wv * 64) * 16;  /* wave-uniform byte */  \
            const int L  = Lu + lane * 16;                                      \
            const int rr = L >> 9;                                              \
            const int sb = (L & 511) ^ ((rr & 7) << 4);                         \
            __builtin_amdgcn_global_load_lds(                                   \
                (AS1 void*)(gb + (size_t)rr * 512 + sb),                        \
                (AS3 void*)(db + Lu), 16, 0, 0);                                \
        }                                                                       \
    } while (0)

    // per-wave compute geometry: rows rloc = (wv>>1)*16 + nrow of the chunk,
    // output cols (ctb+ct)*16 .. ; ctb = (wv&1)*4
    const int rloc = (wv >> 1) * 16 + nrow;
    const int ctb  = (wv & 1) * 4;
    const int xrow = rloc * 512;
    const int rsw  = (rloc & 7) << 4;
    const unsigned char* wrow = Wl + nrow * 256 + ctb * 4096;
    const int wsw = (nrow & 7) << 4;

#define COMPUTE(c) do {                                                          \
        const unsigned char* bb = Xl + ((c) & 1) * CHUNK_B;                     \
        floatx4 acc0 = *(const floatx4*)&blds[(ctb + 0) * 16 + quad * 4];       \
        floatx4 acc1 = *(const floatx4*)&blds[(ctb + 1) * 16 + quad * 4];       \
        floatx4 acc2 = *(const floatx4*)&blds[(ctb + 2) * 16 + quad * 4];       \
        floatx4 acc3 = *(const floatx4*)&blds[(ctb + 3) * 16 + quad * 4];       \
        _Pragma("unroll")                                                       \
        for (int ks = 0; ks < 4; ++ks) {                                        \
            const int kb = ks * 128 + quad * 32;                                \
            floatx4 xa = *(const floatx4*)(bb + xrow + ((kb)      ^ rsw));      \
            floatx4 xb = *(const floatx4*)(bb + xrow + ((kb + 16) ^ rsw));      \
            bf16x8 xf;                                                          \
            xf[0] = (__bf16)xa.x; xf[1] = (__bf16)xa.y;                         \
            xf[2] = (__bf16)xa.z; xf[3] = (__bf16)xa.w;                         \
            xf[4] = (__bf16)xb.x; xf[5] = (__bf16)xb.y;                         \
            xf[6] = (__bf16)xb.z; xf[7] = (__bf16)xb.w;                         \
            const unsigned char* wp = wrow + ((ks * 64 + quad * 16) ^ wsw);     \
            acc0 = __builtin_amdgcn_mfma_f32_16x16x32_bf16(                     \
                       *(const bf16x8*)(wp),         xf, acc0, 0, 0, 0);        \
            acc1 = __builtin_amdgcn_mfma_f32_16x16x32_bf16(                     \
                       *(const bf16x8*)(wp + 4096),  xf, acc1, 0, 0, 0);        \
            acc2 = __builtin_amdgcn_mfma_f32_16x16x32_bf16(                     \
                       *(const bf16x8*)(wp + 8192),  xf, acc2, 0, 0, 0);        \
            acc3 = __builtin_amdgcn_mfma_f32_16x16x32_bf16(                     \
                       *(const bf16x8*)(wp + 12288), xf, acc3, 0, 0, 0);        \
        }                                                                       \
        float* yr = y + (((c) & 8) ? xoff1 : xoff0)                             \
                  + (size_t)(((c) & 7) * 32 + rloc) * 128 + ctb * 16 + quad * 4;\
        __builtin_nontemporal_store(acc0, (floatx4*)(yr));                      \
        __builtin_nontemporal_store(acc1, (floatx4*)(yr + 16));                 \
        __builtin_nontemporal_store(acc2, (floatx4*)(yr + 32));                 \
        __builtin_nontemporal_store(acc3, (floatx4*)(yr + 48));                 \
    } while (0)

    // TAIL(c): barrier (all waves done reading buf c&1) -> issue stage c+2 ->
    // counted vmcnt: own chunk-c+1 loads drained (stores_c=4 [+ stage_{c+2}=4]
    // newest stay in flight) -> barrier (chunk c+1 visible to all).
#define TAIL(WNLIT, DOSTAGE, c) do {                                            \
        __builtin_amdgcn_sched_barrier(0);                                      \
        __builtin_amdgcn_s_barrier();                                           \
        if (DOSTAGE) STAGE((c) + 2);                                            \
        asm volatile("s_waitcnt vmcnt(" WNLIT ")" ::: "memory");                \
        __builtin_amdgcn_sched_barrier(0);                                      \
        __builtin_amdgcn_s_barrier();                                           \
    } while (0)

    // ---- prologue: stage chunks 0,1; wait own chunk0 (leave chunk1 flying) ----
    STAGE(0);
    STAGE(1);
    asm volatile("s_waitcnt vmcnt(4) lgkmcnt(0)" ::: "memory");
    __builtin_amdgcn_sched_barrier(0);
    __builtin_amdgcn_s_barrier();

    // ---- steady state: chunks 0..13 keep 1 chunk in flight ----
    #pragma unroll 2
    for (int c = 0; c < 14; ++c) {
        COMPUTE(c);
        TAIL("8", 1, c);
    }
    COMPUTE(14);
    TAIL("4", 0, 14);
    COMPUTE(15);

#undef STAGE
#undef COMPUTE
#undef TAIL
}

extern "C" void kernel_launch(void* const* d_in, const int* in_sizes, int n_in,
                              void* d_out, int out_size, void* d_ws, size_t ws_size,
                              hipStream_t stream) {
    const float* x = (const float*)d_in[0];
    const float* W = (const float*)d_in[1];
    const float* b = (const float*)d_in[2];
    float* y = (float*)d_out;
    dim3 grid(512), block(256);
    hipLaunchKernelGGL(mcsl_kernel, grid, block, 0, stream, x, W, b, y);
}